// Round 6
// baseline (768.568 us; speedup 1.0000x reference)
//
#include <hip/hip_runtime.h>

// Problem constants
#define NDRUG 50000
#define NDIS  50000
#define RR    5
#define FF    128
#define EFFD  128
#define OUTD  64
#define EE    400000
#define NCOL  (RR * OUTD)        // 320 columns in fused g / out layout [n][r*64+o]
#define NB    (RR * NDIS)        // 250000 bins per direction
#define NEDGE (RR * EE)          // 2,000,000 edges per direction
#define NCHUNKS 500              // 2*NB / 1000 chunks of 1000 (dir boundary at chunk 250)

// XCD partitioning for hist/scatter: 8 partitions = dir(2) x dst-quarter(4)
#define NPART   8
#define DPART4  (NDIS / 4)       // 12500 dst per quarter
#define NCHUNKE 64               // edge chunks per r
#define CHUNKE  (EE / NCHUNKE)   // 6250 edges per chunk

typedef unsigned short ushort_t;
typedef unsigned int uint_t;
typedef short short8 __attribute__((ext_vector_type(8)));
typedef float f32x4 __attribute__((ext_vector_type(4)));

// f32 -> bf16 round-to-nearest-even
static __device__ __forceinline__ ushort_t f2bf(float f) {
    uint_t u = __float_as_uint(f);
    uint_t r = (u + 0x7FFFu + ((u >> 16) & 1u)) >> 16;
    return (ushort_t)r;
}
static __device__ __forceinline__ float bf2f(ushort_t u) {
    return __uint_as_float(((uint_t)u) << 16);
}

// ---------------------------------------------------------------------------
// Kernel A: Mt[col][f] = bf16( sum_e (att[r,0]*basis[0,f,e]+att[r,1]*basis[1,f,e]) * fc_w[e,o] )
// col = r*64+o. Transposed+bf16 so the MFMA B-fragment is contiguous in k(=f).
// ---------------------------------------------------------------------------
__global__ __launch_bounds__(256) void k_make_M(const float* __restrict__ att,
                                                const float* __restrict__ basis,
                                                const float* __restrict__ fcw,
                                                ushort_t* __restrict__ Mt) {
    int tid = blockIdx.x * 256 + threadIdx.x;
    if (tid >= RR * FF * OUTD) return;
    int r = tid / (FF * OUTD);
    int rem = tid - r * FF * OUTD;
    int f = rem >> 6;
    int o = rem & 63;
    float a0 = att[r * 2 + 0], a1 = att[r * 2 + 1];
    const float* b0 = basis + f * EFFD;
    const float* b1 = basis + FF * EFFD + f * EFFD;
    float acc = 0.f;
#pragma unroll 4
    for (int e = 0; e < EFFD; ++e) {
        float w = a0 * b0[e] + a1 * b1[e];
        acc += w * fcw[e * OUTD + o];
    }
    Mt[(size_t)(r * OUTD + o) * FF + f] = f2bf(acc);
}

// ---------------------------------------------------------------------------
// Kernel B (MFMA): g[n][col] = bf16( cj[n] * sum_k feat[n][k] * M[k][col] )
// Block: 64 rows x 160 cols, 4 waves. blockIdx.y = col half, blockIdx.z = side.
// ---------------------------------------------------------------------------
__global__ __launch_bounds__(256) void k_gemm(const float* __restrict__ featA,
                                              const float* __restrict__ cjA,
                                              const float* __restrict__ featB,
                                              const float* __restrict__ cjB,
                                              const ushort_t* __restrict__ Mt,
                                              ushort_t* __restrict__ gA,
                                              ushort_t* __restrict__ gB) {
    const float* feat; const float* cj; ushort_t* g;
    if (blockIdx.z == 0) { feat = featA; cj = cjA; g = gA; }
    else                 { feat = featB; cj = cjB; g = gB; }

    __shared__ ushort_t featS[64][136];
    __shared__ ushort_t mtS[160][136];

    const int tid  = threadIdx.x;
    const int row0 = blockIdx.x * 64;
    const int ch0  = blockIdx.y * 160;    // column-half base

    // Stage feat tile: 64 rows x 128 f32 -> bf16 LDS
    for (int i = tid; i < 64 * 32; i += 256) {
        int r  = i >> 5;
        int c4 = (i & 31) << 2;
        float4 v = make_float4(0.f, 0.f, 0.f, 0.f);
        int row = row0 + r;
        if (row < NDRUG) v = *(const float4*)(feat + (size_t)row * FF + c4);
        ushort4 pk;
        pk.x = f2bf(v.x); pk.y = f2bf(v.y); pk.z = f2bf(v.z); pk.w = f2bf(v.w);
        *(ushort4*)&featS[r][c4] = pk;
    }
    // Stage Mt slice: 160 cols x 128 k (bf16, contiguous 256B rows)
    for (int i = tid; i < 160 * 16; i += 256) {
        int c  = i >> 4;        // col within slice
        int q8 = (i & 15) << 3; // ushort offset (16B chunks)
        *(short8*)&mtS[c][q8] = *(const short8*)(Mt + (size_t)(ch0 + c) * FF + q8);
    }
    __syncthreads();

    const int w = tid >> 6;      // wave 0..3 -> rows w*16..w*16+15
    const int l = tid & 63;
    const int lr = l & 15;       // fragment row/col index
    const int lg = l >> 4;       // k-group

    short8 afrag[4];
#pragma unroll
    for (int ks = 0; ks < 4; ++ks)
        afrag[ks] = *(const short8*)&featS[w * 16 + lr][ks * 32 + lg * 8];

    const int rbase = row0 + w * 16 + (lg << 2);
    float cjv[4];
#pragma unroll
    for (int rg = 0; rg < 4; ++rg)
        cjv[rg] = (rbase + rg < NDRUG) ? cj[rbase + rg] : 0.f;

#pragma unroll
    for (int n = 0; n < 10; ++n) {
        f32x4 c = {0.f, 0.f, 0.f, 0.f};
#pragma unroll
        for (int ks = 0; ks < 4; ++ks) {
            short8 b = *(const short8*)&mtS[n * 16 + lr][ks * 32 + lg * 8];
            c = __builtin_amdgcn_mfma_f32_16x16x32_bf16(afrag[ks], b, c, 0, 0, 0);
        }
        int col = ch0 + n * 16 + lr;
#pragma unroll
        for (int rg = 0; rg < 4; ++rg) {
            int row = rbase + rg;
            if (row < NDRUG)
                g[(size_t)row * NCOL + col] = f2bf(c[rg] * cjv[rg]);
        }
    }
}

// ---------------------------------------------------------------------------
// CSR build: XCD-partitioned histogram -> chunked exclusive scan -> scatter
// bins layout: [dir][r*NDIS + dst], flat 2*NB ints.
// dir 0: drug->dis (dst = edge_dis, src = edge_drug)
// dir 1: dis->drug (dst = edge_drug, src = edge_dis)
// grid: (NCHUNKE*NPART, RR); partition p = blockIdx.x & 7 encodes
// dir = p>>2, dst-quarter = p&3. All atomics/writes for a bin region come
// from one XCD (round-robin blockIdx->XCD; gridDim.x % 8 == 0). Each edge
// array element is read 4x (by the 4 quarters of its dir), not 8x.
// ---------------------------------------------------------------------------
__global__ __launch_bounds__(256) void k_hist(const int* __restrict__ ed,
                                              const int* __restrict__ ei,
                                              int* __restrict__ bins) {
    int p = blockIdx.x & (NPART - 1);
    int dir = p >> 2;
    int quarter = p & 3;
    int chunk = blockIdx.x >> 3;
    int r = blockIdx.y;
    const int* dstarr = (dir ? ed : ei) + (size_t)r * EE;
    int* b = bins + dir * NB + r * NDIS;
    int lo = quarter * DPART4, hi = lo + DPART4;
    int e0 = chunk * CHUNKE;
    for (int i = e0 + threadIdx.x; i < e0 + CHUNKE; i += 256) {
        int d = dstarr[i];
        if (d >= lo && d < hi) atomicAdd(&b[d], 1);
    }
}

__global__ __launch_bounds__(256) void k_scan1(const int* __restrict__ bins,
                                               int* __restrict__ partial) {
    int b = blockIdx.x;           // 0..499, chunk of 1000
    int base = b * 1000;
    int t = threadIdx.x;
    int s = 0;
#pragma unroll
    for (int j = 0; j < 4; ++j) {
        int k = t * 4 + j;
        if (k < 1000) s += bins[base + k];
    }
    __shared__ int lds[256];
    lds[t] = s;
    __syncthreads();
    for (int off = 128; off; off >>= 1) {
        if (t < off) lds[t] += lds[t + off];
        __syncthreads();
    }
    if (t == 0) partial[b] = lds[0];
}

__global__ __launch_bounds__(512) void k_scan2(const int* __restrict__ partial,
                                               int* __restrict__ cofs) {
    __shared__ int lds[NCHUNKS];
    int t = threadIdx.x;
    if (t < NCHUNKS) lds[t] = partial[t];
    __syncthreads();
    if (t < 2) {                   // independent scan per direction (250 chunks each)
        int acc = 0;
        for (int c = 0; c < 250; ++c) {
            int v = lds[t * 250 + c];
            cofs[t * 250 + c] = acc;
            acc += v;
        }
    }
}

__global__ __launch_bounds__(256) void k_scan3(int* __restrict__ bins,
                                               const int* __restrict__ cofs) {
    int b = blockIdx.x, t = threadIdx.x, base = b * 1000;
    int v[4]; int mysum = 0;
#pragma unroll
    for (int j = 0; j < 4; ++j) {
        int k = t * 4 + j;
        v[j] = (k < 1000) ? bins[base + k] : 0;
        mysum += v[j];
    }
    __shared__ int lds[256];
    lds[t] = mysum;
    __syncthreads();
    for (int off = 1; off < 256; off <<= 1) {
        int x = (t >= off) ? lds[t - off] : 0;
        __syncthreads();
        lds[t] += x;
        __syncthreads();
    }
    int run = lds[t] - mysum + cofs[b];
#pragma unroll
    for (int j = 0; j < 4; ++j) {
        int k = t * 4 + j;
        if (k < 1000) { bins[base + k] = run; run += v[j]; }
    }
}

// sorted must be zeroed beforehand; each position is written exactly once via
// atomicOr of the 16-bit src into its containing 32-bit word -> the RMW
// allocates the line in the XCD-local L2 (no partial-line write-through).
__global__ __launch_bounds__(256) void k_scatter(const int* __restrict__ ed,
                                                 const int* __restrict__ ei,
                                                 int* __restrict__ bins,
                                                 uint_t* __restrict__ sorted32) {
    int p = blockIdx.x & (NPART - 1);
    int dir = p >> 2;
    int quarter = p & 3;
    int chunk = blockIdx.x >> 3;
    int r = blockIdx.y;
    const int* dstarr = (dir ? ed : ei) + (size_t)r * EE;
    const int* srcarr = (dir ? ei : ed) + (size_t)r * EE;
    int* b = bins + dir * NB + r * NDIS;
    uint_t* s32 = sorted32 + (size_t)dir * (NEDGE / 2);
    int lo = quarter * DPART4, hi = lo + DPART4;
    int e0 = chunk * CHUNKE;
    for (int i = e0 + threadIdx.x; i < e0 + CHUNKE; i += 256) {
        int d = dstarr[i];
        if (d >= lo && d < hi) {
            int pos = atomicAdd(&b[d], 1);
            uint_t val = ((uint_t)(ushort_t)srcarr[i]) << ((pos & 1) * 16);
            atomicOr(&s32[pos >> 1], val);
        }
    }
}

// ---------------------------------------------------------------------------
// Gather aggregation + fused epilogue. One wave per (dst, r) bin.
// After scatter, bins[dir][k] = inclusive end of bin k; start = bins[k-1] (0 for k=0).
// ---------------------------------------------------------------------------
__global__ __launch_bounds__(256) void k_agg(const ushort_t* __restrict__ gd,
                                             const ushort_t* __restrict__ gi,
                                             const int* __restrict__ bins,
                                             const ushort_t* __restrict__ sorted,
                                             const float* __restrict__ ci_drug,
                                             const float* __restrict__ ci_dis,
                                             const float* __restrict__ fcb,
                                             float* __restrict__ out_drug,
                                             float* __restrict__ out_dis) {
    int dir = blockIdx.y;
    const ushort_t* g   = dir ? gi : gd;
    const float* ci     = dir ? ci_drug : ci_dis;
    float* outp         = dir ? out_drug : out_dis;
    const int* bn       = bins + dir * NB;
    const ushort_t* srt = sorted + (size_t)dir * NEDGE;

    int wave = blockIdx.x * 4 + (threadIdx.x >> 6);
    int lane = threadIdx.x & 63;
    if (wave >= NB) return;
    int r = wave / NDIS;
    int dst = wave - r * NDIS;
    int start = wave ? bn[wave - 1] : 0;
    int end = bn[wave];
    int colbase = r * OUTD + lane;

    float acc = 0.f;
    for (int base = start; base < end; base += 64) {
        int m = end - base; if (m > 64) m = 64;
        // one coalesced load: lane i holds src index of edge base+i (clamped)
        int li = lane < m ? lane : m - 1;
        int my = (int)srt[base + li];
        for (int j = 0; j < m; j += 8) {
            float part = 0.f;
#pragma unroll
            for (int k = 0; k < 8; ++k) {
                int jj = j + k;
                int cl = jj < m ? jj : m - 1;        // wave-uniform
                int sj = __shfl(my, cl);
                float v = bf2f(g[(size_t)sj * NCOL + colbase]);
                part += (jj < m) ? v : 0.f;
            }
            acc += part;
        }
    }
    outp[(size_t)dst * NCOL + colbase] = acc * ci[dst] + fcb[lane];
}

// ---------------------------------------------------------------------------
extern "C" void kernel_launch(void* const* d_in, const int* in_sizes, int n_in,
                              void* d_out, int out_size, void* d_ws, size_t ws_size,
                              hipStream_t stream) {
    const float* drug_feat = (const float*)d_in[0];
    const float* dis_feat  = (const float*)d_in[1];
    const float* cj_drug   = (const float*)d_in[2];
    const float* ci_drug   = (const float*)d_in[3];
    const float* cj_dis    = (const float*)d_in[4];
    const float* ci_dis    = (const float*)d_in[5];
    const float* att       = (const float*)d_in[6];
    const float* basis     = (const float*)d_in[7];
    const float* fcw       = (const float*)d_in[8];
    const float* fcb       = (const float*)d_in[9];
    const int*   edge_drug = (const int*)d_in[10];
    const int*   edge_dis  = (const int*)d_in[11];

    float* out      = (float*)d_out;
    float* out_drug = out;
    float* out_dis  = out + (size_t)NDRUG * NCOL;

    // Workspace layout (~74.2 MB):
    char* ws = (char*)d_ws;
    ushort_t* gd      = (ushort_t*)ws;
    ushort_t* gi      = (ushort_t*)(ws + 32000000);
    ushort_t* Mtb     = (ushort_t*)(ws + 64000000);   // bf16 Mt [320][128]
    int*      bins    = (int*)(ws + 64200000);
    int*      partial = (int*)(ws + 66200000);
    int*      cofs    = (int*)(ws + 66204000);
    ushort_t* sorted  = (ushort_t*)(ws + 66208000);

    // zero histogram + sorted (atomicOr target)
    hipMemsetAsync(bins, 0, 2 * NB * sizeof(int), stream);
    hipMemsetAsync(sorted, 0, (size_t)2 * NEDGE * sizeof(ushort_t), stream);

    // A: fused att*basis*fc_w -> Mt bf16 [320][128]
    k_make_M<<<dim3((RR * FF * OUTD + 255) / 256), 256, 0, stream>>>(att, basis, fcw, Mtb);

    // B: g = bf16((feat @ M) * cj), both sides (MFMA)
    dim3 ggrid((NDRUG + 63) / 64, 2, 2);
    k_gemm<<<ggrid, 256, 0, stream>>>(drug_feat, cj_drug, dis_feat, cj_dis, Mtb, gd, gi);

    // CSR build (XCD-partitioned hist + scatter; dir folded into partition)
    k_hist<<<dim3(NCHUNKE * NPART, RR), 256, 0, stream>>>(edge_drug, edge_dis, bins);
    k_scan1<<<NCHUNKS, 256, 0, stream>>>(bins, partial);
    k_scan2<<<1, 512, 0, stream>>>(partial, cofs);
    k_scan3<<<NCHUNKS, 256, 0, stream>>>(bins, cofs);
    k_scatter<<<dim3(NCHUNKE * NPART, RR), 256, 0, stream>>>(edge_drug, edge_dis, bins,
                                                             (uint_t*)sorted);

    // Gather aggregation + fused ci-scale + bias
    k_agg<<<dim3((NB + 3) / 4, 2), 256, 0, stream>>>(gd, gi, bins, sorted,
                                                     ci_drug, ci_dis, fcb,
                                                     out_drug, out_dis);
}

// Round 7
// 595.500 us; speedup vs baseline: 1.2906x; 1.2906x over previous
//
#include <hip/hip_runtime.h>

// Problem constants
#define NDRUG 50000
#define NDIS  50000
#define RR    5
#define FF    128
#define EFFD  128
#define OUTD  64
#define EE    400000
#define NCOL  (RR * OUTD)        // 320 columns in fused g / out layout [n][r*64+o]
#define NB    (RR * NDIS)        // 250000 bins per direction
#define NEDGE (RR * EE)          // 2,000,000 edges per direction
#define NCHUNKS 500              // 2*NB / 1000 chunks of 1000 (dir boundary at chunk 250)

// XCD partitioning for hist/scatter: 8 partitions = dir(2) x dst-quarter(4)
#define NPART   8
#define DPART4  (NDIS / 4)       // 12500 dst per quarter
#define NCHUNKE 64               // edge chunks per r
#define CHUNKE  (EE / NCHUNKE)   // 6250 edges per chunk

typedef unsigned short ushort_t;
typedef unsigned int uint_t;
typedef short short8 __attribute__((ext_vector_type(8)));
typedef float f32x4 __attribute__((ext_vector_type(4)));

// f32 -> bf16 round-to-nearest-even
static __device__ __forceinline__ ushort_t f2bf(float f) {
    uint_t u = __float_as_uint(f);
    uint_t r = (u + 0x7FFFu + ((u >> 16) & 1u)) >> 16;
    return (ushort_t)r;
}
static __device__ __forceinline__ float bf2f(ushort_t u) {
    return __uint_as_float(((uint_t)u) << 16);
}

// ---------------------------------------------------------------------------
// Kernel A: Mt[col][f] = bf16( sum_e (att[r,0]*basis[0,f,e]+att[r,1]*basis[1,f,e]) * fc_w[e,o] )
// col = r*64+o. Transposed+bf16 so the MFMA B-fragment is contiguous in k(=f).
// ---------------------------------------------------------------------------
__global__ __launch_bounds__(256) void k_make_M(const float* __restrict__ att,
                                                const float* __restrict__ basis,
                                                const float* __restrict__ fcw,
                                                ushort_t* __restrict__ Mt) {
    int tid = blockIdx.x * 256 + threadIdx.x;
    if (tid >= RR * FF * OUTD) return;
    int r = tid / (FF * OUTD);
    int rem = tid - r * FF * OUTD;
    int f = rem >> 6;
    int o = rem & 63;
    float a0 = att[r * 2 + 0], a1 = att[r * 2 + 1];
    const float* b0 = basis + f * EFFD;
    const float* b1 = basis + FF * EFFD + f * EFFD;
    float acc = 0.f;
#pragma unroll 4
    for (int e = 0; e < EFFD; ++e) {
        float w = a0 * b0[e] + a1 * b1[e];
        acc += w * fcw[e * OUTD + o];
    }
    Mt[(size_t)(r * OUTD + o) * FF + f] = f2bf(acc);
}

// ---------------------------------------------------------------------------
// Kernel B (MFMA): g[n][col] = bf16( cj[n] * sum_k feat[n][k] * M[k][col] )
// Block: 64 rows x 160 cols, 4 waves. blockIdx.y = col half, blockIdx.z = side.
// ---------------------------------------------------------------------------
__global__ __launch_bounds__(256) void k_gemm(const float* __restrict__ featA,
                                              const float* __restrict__ cjA,
                                              const float* __restrict__ featB,
                                              const float* __restrict__ cjB,
                                              const ushort_t* __restrict__ Mt,
                                              ushort_t* __restrict__ gA,
                                              ushort_t* __restrict__ gB) {
    const float* feat; const float* cj; ushort_t* g;
    if (blockIdx.z == 0) { feat = featA; cj = cjA; g = gA; }
    else                 { feat = featB; cj = cjB; g = gB; }

    __shared__ ushort_t featS[64][136];
    __shared__ ushort_t mtS[160][136];

    const int tid  = threadIdx.x;
    const int row0 = blockIdx.x * 64;
    const int ch0  = blockIdx.y * 160;    // column-half base

    // Stage feat tile: 64 rows x 128 f32 -> bf16 LDS
    for (int i = tid; i < 64 * 32; i += 256) {
        int r  = i >> 5;
        int c4 = (i & 31) << 2;
        float4 v = make_float4(0.f, 0.f, 0.f, 0.f);
        int row = row0 + r;
        if (row < NDRUG) v = *(const float4*)(feat + (size_t)row * FF + c4);
        ushort4 pk;
        pk.x = f2bf(v.x); pk.y = f2bf(v.y); pk.z = f2bf(v.z); pk.w = f2bf(v.w);
        *(ushort4*)&featS[r][c4] = pk;
    }
    // Stage Mt slice: 160 cols x 128 k (bf16, contiguous 256B rows)
    for (int i = tid; i < 160 * 16; i += 256) {
        int c  = i >> 4;        // col within slice
        int q8 = (i & 15) << 3; // ushort offset (16B chunks)
        *(short8*)&mtS[c][q8] = *(const short8*)(Mt + (size_t)(ch0 + c) * FF + q8);
    }
    __syncthreads();

    const int w = tid >> 6;      // wave 0..3 -> rows w*16..w*16+15
    const int l = tid & 63;
    const int lr = l & 15;       // fragment row/col index
    const int lg = l >> 4;       // k-group

    short8 afrag[4];
#pragma unroll
    for (int ks = 0; ks < 4; ++ks)
        afrag[ks] = *(const short8*)&featS[w * 16 + lr][ks * 32 + lg * 8];

    const int rbase = row0 + w * 16 + (lg << 2);
    float cjv[4];
#pragma unroll
    for (int rg = 0; rg < 4; ++rg)
        cjv[rg] = (rbase + rg < NDRUG) ? cj[rbase + rg] : 0.f;

#pragma unroll
    for (int n = 0; n < 10; ++n) {
        f32x4 c = {0.f, 0.f, 0.f, 0.f};
#pragma unroll
        for (int ks = 0; ks < 4; ++ks) {
            short8 b = *(const short8*)&mtS[n * 16 + lr][ks * 32 + lg * 8];
            c = __builtin_amdgcn_mfma_f32_16x16x32_bf16(afrag[ks], b, c, 0, 0, 0);
        }
        int col = ch0 + n * 16 + lr;
#pragma unroll
        for (int rg = 0; rg < 4; ++rg) {
            int row = rbase + rg;
            if (row < NDRUG)
                g[(size_t)row * NCOL + col] = f2bf(c[rg] * cjv[rg]);
        }
    }
}

// ---------------------------------------------------------------------------
// CSR build: XCD-partitioned histogram -> chunked exclusive scan -> scatter
// bins layout: [dir][r*NDIS + dst], flat 2*NB ints.
// dir 0: drug->dis (dst = edge_dis, src = edge_drug)
// dir 1: dis->drug (dst = edge_drug, src = edge_dis)
// grid: (NCHUNKE*NPART, RR); partition p = blockIdx.x & 7 encodes
// dir = p>>2, dst-quarter = p&3. Edge streams use NONTEMPORAL loads so they
// don't allocate in L2 -> the bins + sorted working set stays L2-resident
// and scattered stores write-combine instead of thrashing to HBM.
// ---------------------------------------------------------------------------
__global__ __launch_bounds__(256) void k_hist(const int* __restrict__ ed,
                                              const int* __restrict__ ei,
                                              int* __restrict__ bins) {
    int p = blockIdx.x & (NPART - 1);
    int dir = p >> 2;
    int quarter = p & 3;
    int chunk = blockIdx.x >> 3;
    int r = blockIdx.y;
    const int* dstarr = (dir ? ed : ei) + (size_t)r * EE;
    int* b = bins + dir * NB + r * NDIS;
    int lo = quarter * DPART4, hi = lo + DPART4;
    int e0 = chunk * CHUNKE;
    for (int i = e0 + threadIdx.x; i < e0 + CHUNKE; i += 256) {
        int d = __builtin_nontemporal_load(dstarr + i);
        if (d >= lo && d < hi) atomicAdd(&b[d], 1);
    }
}

__global__ __launch_bounds__(256) void k_scan1(const int* __restrict__ bins,
                                               int* __restrict__ partial) {
    int b = blockIdx.x;           // 0..499, chunk of 1000
    int base = b * 1000;
    int t = threadIdx.x;
    int s = 0;
#pragma unroll
    for (int j = 0; j < 4; ++j) {
        int k = t * 4 + j;
        if (k < 1000) s += bins[base + k];
    }
    __shared__ int lds[256];
    lds[t] = s;
    __syncthreads();
    for (int off = 128; off; off >>= 1) {
        if (t < off) lds[t] += lds[t + off];
        __syncthreads();
    }
    if (t == 0) partial[b] = lds[0];
}

__global__ __launch_bounds__(512) void k_scan2(const int* __restrict__ partial,
                                               int* __restrict__ cofs) {
    __shared__ int lds[NCHUNKS];
    int t = threadIdx.x;
    if (t < NCHUNKS) lds[t] = partial[t];
    __syncthreads();
    if (t < 2) {                   // independent scan per direction (250 chunks each)
        int acc = 0;
        for (int c = 0; c < 250; ++c) {
            int v = lds[t * 250 + c];
            cofs[t * 250 + c] = acc;
            acc += v;
        }
    }
}

__global__ __launch_bounds__(256) void k_scan3(int* __restrict__ bins,
                                               const int* __restrict__ cofs) {
    int b = blockIdx.x, t = threadIdx.x, base = b * 1000;
    int v[4]; int mysum = 0;
#pragma unroll
    for (int j = 0; j < 4; ++j) {
        int k = t * 4 + j;
        v[j] = (k < 1000) ? bins[base + k] : 0;
        mysum += v[j];
    }
    __shared__ int lds[256];
    lds[t] = mysum;
    __syncthreads();
    for (int off = 1; off < 256; off <<= 1) {
        int x = (t >= off) ? lds[t - off] : 0;
        __syncthreads();
        lds[t] += x;
        __syncthreads();
    }
    int run = lds[t] - mysum + cofs[b];
#pragma unroll
    for (int j = 0; j < 4; ++j) {
        int k = t * 4 + j;
        if (k < 1000) { bins[base + k] = run; run += v[j]; }
    }
}

__global__ __launch_bounds__(256) void k_scatter(const int* __restrict__ ed,
                                                 const int* __restrict__ ei,
                                                 int* __restrict__ bins,
                                                 ushort_t* __restrict__ sorted) {
    int p = blockIdx.x & (NPART - 1);
    int dir = p >> 2;
    int quarter = p & 3;
    int chunk = blockIdx.x >> 3;
    int r = blockIdx.y;
    const int* dstarr = (dir ? ed : ei) + (size_t)r * EE;
    const int* srcarr = (dir ? ei : ed) + (size_t)r * EE;
    int* b = bins + dir * NB + r * NDIS;
    ushort_t* s = sorted + (size_t)dir * NEDGE;
    int lo = quarter * DPART4, hi = lo + DPART4;
    int e0 = chunk * CHUNKE;
    for (int i = e0 + threadIdx.x; i < e0 + CHUNKE; i += 256) {
        int d = __builtin_nontemporal_load(dstarr + i);
        if (d >= lo && d < hi) {
            int src = __builtin_nontemporal_load(srcarr + i);
            int pos = atomicAdd(&b[d], 1);
            s[pos] = (ushort_t)src;
        }
    }
}

// ---------------------------------------------------------------------------
// Gather aggregation + fused epilogue. One wave per (dst, r) bin.
// After scatter, bins[dir][k] = inclusive end of bin k; start = bins[k-1] (0 for k=0).
// ---------------------------------------------------------------------------
__global__ __launch_bounds__(256) void k_agg(const ushort_t* __restrict__ gd,
                                             const ushort_t* __restrict__ gi,
                                             const int* __restrict__ bins,
                                             const ushort_t* __restrict__ sorted,
                                             const float* __restrict__ ci_drug,
                                             const float* __restrict__ ci_dis,
                                             const float* __restrict__ fcb,
                                             float* __restrict__ out_drug,
                                             float* __restrict__ out_dis) {
    int dir = blockIdx.y;
    const ushort_t* g   = dir ? gi : gd;
    const float* ci     = dir ? ci_drug : ci_dis;
    float* outp         = dir ? out_drug : out_dis;
    const int* bn       = bins + dir * NB;
    const ushort_t* srt = sorted + (size_t)dir * NEDGE;

    int wave = blockIdx.x * 4 + (threadIdx.x >> 6);
    int lane = threadIdx.x & 63;
    if (wave >= NB) return;
    int r = wave / NDIS;
    int dst = wave - r * NDIS;
    int start = wave ? bn[wave - 1] : 0;
    int end = bn[wave];
    int colbase = r * OUTD + lane;

    float acc = 0.f;
    for (int base = start; base < end; base += 64) {
        int m = end - base; if (m > 64) m = 64;
        // one coalesced load: lane i holds src index of edge base+i (clamped)
        int li = lane < m ? lane : m - 1;
        int my = (int)srt[base + li];
        for (int j = 0; j < m; j += 8) {
            float part = 0.f;
#pragma unroll
            for (int k = 0; k < 8; ++k) {
                int jj = j + k;
                int cl = jj < m ? jj : m - 1;        // wave-uniform
                int sj = __shfl(my, cl);
                float v = bf2f(g[(size_t)sj * NCOL + colbase]);
                part += (jj < m) ? v : 0.f;
            }
            acc += part;
        }
    }
    outp[(size_t)dst * NCOL + colbase] = acc * ci[dst] + fcb[lane];
}

// ---------------------------------------------------------------------------
extern "C" void kernel_launch(void* const* d_in, const int* in_sizes, int n_in,
                              void* d_out, int out_size, void* d_ws, size_t ws_size,
                              hipStream_t stream) {
    const float* drug_feat = (const float*)d_in[0];
    const float* dis_feat  = (const float*)d_in[1];
    const float* cj_drug   = (const float*)d_in[2];
    const float* ci_drug   = (const float*)d_in[3];
    const float* cj_dis    = (const float*)d_in[4];
    const float* ci_dis    = (const float*)d_in[5];
    const float* att       = (const float*)d_in[6];
    const float* basis     = (const float*)d_in[7];
    const float* fcw       = (const float*)d_in[8];
    const float* fcb       = (const float*)d_in[9];
    const int*   edge_drug = (const int*)d_in[10];
    const int*   edge_dis  = (const int*)d_in[11];

    float* out      = (float*)d_out;
    float* out_drug = out;
    float* out_dis  = out + (size_t)NDRUG * NCOL;

    // Workspace layout (~74.2 MB):
    char* ws = (char*)d_ws;
    ushort_t* gd      = (ushort_t*)ws;
    ushort_t* gi      = (ushort_t*)(ws + 32000000);
    ushort_t* Mtb     = (ushort_t*)(ws + 64000000);   // bf16 Mt [320][128]
    int*      bins    = (int*)(ws + 64200000);
    int*      partial = (int*)(ws + 66200000);
    int*      cofs    = (int*)(ws + 66204000);
    ushort_t* sorted  = (ushort_t*)(ws + 66208000);

    // zero histogram
    hipMemsetAsync(bins, 0, 2 * NB * sizeof(int), stream);

    // A: fused att*basis*fc_w -> Mt bf16 [320][128]
    k_make_M<<<dim3((RR * FF * OUTD + 255) / 256), 256, 0, stream>>>(att, basis, fcw, Mtb);

    // B: g = bf16((feat @ M) * cj), both sides (MFMA)
    dim3 ggrid((NDRUG + 63) / 64, 2, 2);
    k_gemm<<<ggrid, 256, 0, stream>>>(drug_feat, cj_drug, dis_feat, cj_dis, Mtb, gd, gi);

    // CSR build (XCD-partitioned hist + scatter; NT edge streams)
    k_hist<<<dim3(NCHUNKE * NPART, RR), 256, 0, stream>>>(edge_drug, edge_dis, bins);
    k_scan1<<<NCHUNKS, 256, 0, stream>>>(bins, partial);
    k_scan2<<<1, 512, 0, stream>>>(partial, cofs);
    k_scan3<<<NCHUNKS, 256, 0, stream>>>(bins, cofs);
    k_scatter<<<dim3(NCHUNKE * NPART, RR), 256, 0, stream>>>(edge_drug, edge_dis, bins, sorted);

    // Gather aggregation + fused ci-scale + bias
    k_agg<<<dim3((NB + 3) / 4, 2), 256, 0, stream>>>(gd, gi, bins, sorted,
                                                     ci_drug, ci_dis, fcb,
                                                     out_drug, out_dis);
}